// Round 6
// baseline (341.085 us; speedup 1.0000x reference)
//
#include <hip/hip_runtime.h>
#include <hip/hip_bf16.h>

// Problem: latent (16,192,64,64) fp32, codebook (1024,192) fp32.
// N = 65536 points, D = 192, K = 1024.
// d_out = [quantized: 12582912 fp32][indices-as-float: 65536].

#define NPTS   65536
#define DIMS   192
#define KCB    1024
#define HW     4096
#define QELEMS 12582912

typedef __attribute__((ext_vector_type(8))) _Float16 f16x8;
typedef __attribute__((ext_vector_type(4))) _Float16 f16x4;
typedef __attribute__((ext_vector_type(4))) float f32x4;

// ===================== f16 MFMA path, top-3 + rescue =====================
// A = f16(raw latent) resident in LDS; B = f16(codebook) direct from L2.
// dist+1 = (c2[k]+1) - 2*inv*(A.B)  in [~0.99, 4] -> positive float bits
// are monotone; embed k in the low 10 mantissa bits (quant <= 2.4e-4).
// f16 dist error bound E ~ 2.0e-3. MVAL = 6e-3 >= 2E + 2*quant + slack.
//   gap(1,2) <  MVAL -> exact fp32 rescore of top-3 candidates (k_fix)
//   gap(1,3) <  MVAL -> full 1024-codeword fp32 rescore (k_full), rare.
#define MVAL 6.0e-3f

__device__ __forceinline__ void ins3(unsigned& a, unsigned& b, unsigned& c,
                                     unsigned v) {
    unsigned m1 = max(a, v); a = min(a, v);
    unsigned m2 = max(b, m1); b = min(b, m1);
    c = min(c, m2);
}

// ---- one-shot prep: Bpf (f16 group-major), c2, cbkT ----
__global__ __launch_bounds__(256) void k_prep(const float* __restrict__ cbk,
                                              _Float16* __restrict__ Bpf,
                                              float* __restrict__ c2,
                                              float* __restrict__ cbkT) {
    __shared__ float q[64 * 193];
    const int tid = threadIdx.x;
    const int k0 = blockIdx.x * 64;
    const int lane = tid & 63;
    const int grp = tid >> 6;
    for (int r = grp; r < 64; r += 4) {
        const float* row = cbk + (size_t)(k0 + r) * DIMS;
        for (int c = lane; c < DIMS; c += 64) q[r * 193 + c] = row[c];
    }
    __syncthreads();
    if (tid < 64) {
        float s = 0.f;
        for (int c = 0; c < DIMS; ++c) { float v = q[tid * 193 + c]; s = fmaf(v, v, s); }
        c2[k0 + tid] = s;
    }
    // Bpf[g][k][64]: g = d>>6
    #pragma unroll
    for (int i = 0; i < 12; ++i) {
        int u = i * 256 + tid;              // 3072 f16x4 units
        int kk = u / 48, c4 = u % 48, d0 = c4 * 4;
        f16x4 h = { (_Float16)q[kk * 193 + d0], (_Float16)q[kk * 193 + d0 + 1],
                    (_Float16)q[kk * 193 + d0 + 2], (_Float16)q[kk * 193 + d0 + 3] };
        *(f16x4*)&Bpf[((size_t)(d0 >> 6) * KCB + k0 + kk) * 64 + (d0 & 63)] = h;
    }
    for (int d = grp; d < DIMS; d += 4)
        cbkT[(size_t)d * KCB + k0 + lane] = q[lane * 193 + d];
}

// ---- fused: latent->f16 LDS slab + barrier-free MFMA + top-3 + gather ----
__global__ __launch_bounds__(256, 2) void k_gemm_f2(const float* __restrict__ latent,
                                                    const _Float16* __restrict__ Bpf,
                                                    const float* __restrict__ c2,
                                                    const float* __restrict__ cbk,
                                                    float* __restrict__ out_q,
                                                    float* __restrict__ idxf,
                                                    float* __restrict__ inv_g,
                                                    ushort4* __restrict__ cand4,
                                                    int* __restrict__ list,
                                                    int* __restrict__ cnt) {
    __shared__ __align__(16) char smem[51200];     // As (K-loop) / t3+q (post)
    _Float16* As = (_Float16*)smem;                // 128 x 200 f16
    __shared__ float part[256];
    __shared__ float inv_s[128];
    __shared__ int sidx[128];

    const int tid = threadIdx.x;
    const int wave = tid >> 6;
    const int lane = tid & 63;
    const int quad = lane >> 4;
    const int l15 = lane & 15;
    const int wm = (wave >> 1) * 64;
    const int wn = (wave & 1) * 64;
    const int n0 = blockIdx.x * 128;
    const int bB = n0 >> 12;
    const int hw0 = n0 & 4095;

    // ---- phase 0: load raw latent slab once, f16-convert, ssq ----
    {
        const float* lat = latent + (size_t)bB * DIMS * HW + hw0;
        const int p = tid & 127, ch = tid >> 7;
        float ss = 0.f;
        #pragma unroll 4
        for (int i = 0; i < 24; ++i) {
            int c0 = i * 8 + ch * 4;
            float v0 = lat[(size_t)(c0 + 0) * HW + p];
            float v1 = lat[(size_t)(c0 + 1) * HW + p];
            float v2 = lat[(size_t)(c0 + 2) * HW + p];
            float v3 = lat[(size_t)(c0 + 3) * HW + p];
            ss = fmaf(v0, v0, fmaf(v1, v1, fmaf(v2, v2, fmaf(v3, v3, ss))));
            f16x4 h = { (_Float16)v0, (_Float16)v1, (_Float16)v2, (_Float16)v3 };
            *(f16x4*)&As[p * 200 + c0] = h;
        }
        part[ch * 128 + p] = ss;
        __syncthreads();
        if (tid < 128) {
            float iv = 1.0f / (sqrtf(part[tid] + part[128 + tid]) + 1e-8f);
            inv_s[tid] = iv;
            inv_g[n0 + tid] = iv;
        }
        __syncthreads();
    }

    // preload -2*inv for this thread's 16 accumulator rows
    float minv[16];
    #pragma unroll
    for (int mt = 0; mt < 4; ++mt)
        #pragma unroll
        for (int r = 0; r < 4; ++r)
            minv[mt * 4 + r] = -2.0f * inv_s[wm + mt * 16 + quad * 4 + r];

    unsigned ra[16], rbv[16], rc[16];
    #pragma unroll
    for (int i = 0; i < 16; ++i) { ra[i] = ~0u; rbv[i] = ~0u; rc[i] = ~0u; }

    // ---- barrier-free K-loop: nb (8 strips) x g (3 dim groups) ----
    for (int nb = 0; nb < 8; ++nb) {
        f32x4 acc[4][4];
        #pragma unroll
        for (int mt = 0; mt < 4; ++mt)
            #pragma unroll
            for (int nt = 0; nt < 4; ++nt)
                #pragma unroll
                for (int r = 0; r < 4; ++r) acc[mt][nt][r] = 0.f;

        #pragma unroll
        for (int g = 0; g < 3; ++g) {
            #pragma unroll
            for (int s = 0; s < 2; ++s) {
                f16x8 af[4], bfr[4];
                #pragma unroll
                for (int mt = 0; mt < 4; ++mt) {
                    int m = wm + mt * 16 + l15;
                    af[mt] = *(const f16x8*)&As[m * 200 + g * 64 + s * 32 + quad * 8];
                }
                #pragma unroll
                for (int nt = 0; nt < 4; ++nt) {
                    int n = nb * 128 + wn + nt * 16 + l15;
                    bfr[nt] = *(const f16x8*)&Bpf[((size_t)g * KCB + n) * 64
                                                  + s * 32 + quad * 8];
                }
                #pragma unroll
                for (int mt = 0; mt < 4; ++mt)
                    #pragma unroll
                    for (int nt = 0; nt < 4; ++nt)
                        acc[mt][nt] = __builtin_amdgcn_mfma_f32_16x16x32_f16(
                            af[mt], bfr[nt], acc[mt][nt], 0, 0, 0);
            }
        }

        // epilogue: u = bits(dist+1) top-22 | k ; insert into sorted top-3
        int kbase = nb * 128 + wn;
        float c2p[4];
        unsigned kc[4];
        #pragma unroll
        for (int nt = 0; nt < 4; ++nt) {
            kc[nt] = (unsigned)(kbase + nt * 16 + l15);
            c2p[nt] = c2[kc[nt]] + 1.0f;
        }
        #pragma unroll
        for (int mt = 0; mt < 4; ++mt) {
            #pragma unroll
            for (int r = 0; r < 4; ++r) {
                int i = mt * 4 + r;
                float mi = minv[i];
                #pragma unroll
                for (int nt = 0; nt < 4; ++nt) {
                    float d1 = fmaf(mi, acc[mt][nt][r], c2p[nt]);
                    unsigned u = (__float_as_uint(d1) & 0xFFFFFC00u) | kc[nt];
                    ins3(ra[i], rbv[i], rc[i], u);
                }
            }
        }
    }

    // ---- cross-lane (16-lane butterfly) top-3 merge ----
    #pragma unroll
    for (int i = 0; i < 16; ++i) {
        unsigned a = ra[i], b = rbv[i], c = rc[i];
        #pragma unroll
        for (int off = 1; off < 16; off <<= 1) {
            unsigned oa = __shfl_xor(a, off, 64);
            unsigned ob = __shfl_xor(b, off, 64);
            unsigned oc = __shfl_xor(c, off, 64);
            ins3(a, b, c, oa); ins3(a, b, c, ob); ins3(a, b, c, oc);
        }
        ra[i] = a; rbv[i] = b; rc[i] = c;
    }
    __syncthreads();                    // As dead; t3 overlays smem
    unsigned* t3 = (unsigned*)smem;     // [128][2][3]
    #pragma unroll
    for (int i = 0; i < 16; ++i) {
        if (l15 == 0) {
            int mt = i >> 2, r = i & 3;
            int m = wm + mt * 16 + quad * 4 + r;
            t3[(m * 2 + (wave & 1)) * 3 + 0] = ra[i];
            t3[(m * 2 + (wave & 1)) * 3 + 1] = rbv[i];
            t3[(m * 2 + (wave & 1)) * 3 + 2] = rc[i];
        }
    }
    __syncthreads();
    if (tid < 128) {
        unsigned a = t3[(tid * 2) * 3], b = t3[(tid * 2) * 3 + 1], c = t3[(tid * 2) * 3 + 2];
        ins3(a, b, c, t3[(tid * 2 + 1) * 3 + 0]);
        ins3(a, b, c, t3[(tid * 2 + 1) * 3 + 1]);
        ins3(a, b, c, t3[(tid * 2 + 1) * 3 + 2]);
        int k1 = (int)(a & 1023u);
        sidx[tid] = k1;
        idxf[n0 + tid] = (float)k1;
        float d1v = __uint_as_float(a & 0xFFFFFC00u);
        float d2v = __uint_as_float(b & 0xFFFFFC00u);
        float d3v = __uint_as_float(c & 0xFFFFFC00u);
        unsigned fl = ((d2v - d1v) < MVAL ? 1u : 0u) | ((d3v - d1v) < MVAL ? 2u : 0u);
        cand4[n0 + tid] = make_ushort4((ushort)k1, (ushort)(b & 1023u),
                                       (ushort)(c & 1023u), (ushort)fl);
        if (fl & 2u) { int pos = atomicAdd(cnt, 1); list[pos] = n0 + tid; }
    }
    __syncthreads();

    // ---- gather epilogue (q overlays smem) ----
    float* q = (float*)smem;            // 32*193*4 = 24.7 KB
    for (int chk = 0; chk < 4; ++chk) {
        int p0 = chk * 32;
        for (int r = wave; r < 32; r += 4) {
            const float* row = cbk + (size_t)sidx[p0 + r] * DIMS;
            for (int c = lane; c < DIMS; c += 64) q[r * 193 + c] = row[c];
        }
        __syncthreads();
        float* ob = out_q + (size_t)bB * DIMS * HW + hw0 + p0;
        #pragma unroll
        for (int i = 0; i < 24; ++i) {
            int u = i * 256 + tid;
            int c = u >> 5, p = u & 31;
            ob[(size_t)c * HW + p] = q[p * 193 + c];
        }
        __syncthreads();
    }
}

// ---- per-block exact fp32 rescore of top-3 candidates ----
__global__ __launch_bounds__(256) void k_fix(const float* __restrict__ latent,
                                             const float* __restrict__ cbk,
                                             const float* __restrict__ c2,
                                             const float* __restrict__ inv_g,
                                             const ushort4* __restrict__ cand4,
                                             float* __restrict__ out_q,
                                             float* __restrict__ idxf) {
    __shared__ float xs[64 * 193];
    __shared__ ushort4 scand[64];
    __shared__ float pd[64][3];
    __shared__ int plist[64];
    __shared__ int fcnt;
    const int tid = threadIdx.x;

    for (int h = 0; h < 2; ++h) {
        const int base = blockIdx.x * 128 + h * 64;
        __syncthreads();
        if (tid == 0) fcnt = 0;
        __syncthreads();
        if (tid < 64) {
            ushort4 cc = cand4[base + tid];
            scand[tid] = cc;
            if (cc.w & 1) { int pos = atomicAdd(&fcnt, 1); plist[pos] = tid; }
        }
        __syncthreads();
        const int F = fcnt;
        if (F == 0) continue;

        const int bB = base >> 12, hw0 = base & 4095;
        const float* lat = latent + (size_t)bB * DIMS * HW + hw0;
        const int p = tid & 63, c4 = tid >> 6;
        for (int i = 0; i < 48; ++i) {
            int c = c4 + i * 4;
            xs[p * 193 + c] = lat[(size_t)c * HW + p];    // coalesced, LLC-hot
        }
        __syncthreads();

        if (tid < 3 * F) {
            int i = tid / 3, cd = tid - 3 * i;
            int pt = plist[i];
            ushort4 cc = scand[pt];
            int k = (cd == 0) ? cc.x : ((cd == 1) ? cc.y : cc.z);
            const float4* crow = (const float4*)(cbk + (size_t)k * DIMS);
            float dot = 0.f;
            #pragma unroll 8
            for (int d4 = 0; d4 < 48; ++d4) {
                float4 cv = crow[d4];
                const float* xr = &xs[pt * 193 + d4 * 4];
                dot = fmaf(xr[0], cv.x, dot);
                dot = fmaf(xr[1], cv.y, dot);
                dot = fmaf(xr[2], cv.z, dot);
                dot = fmaf(xr[3], cv.w, dot);
            }
            pd[pt][cd] = c2[k] - 2.f * inv_g[base + pt] * dot;
        }
        __syncthreads();
        if (tid < F) {
            int pt = plist[tid];
            ushort4 cc = scand[pt];
            int k[3] = { cc.x, cc.y, cc.z };
            float d[3] = { pd[pt][0], pd[pt][1], pd[pt][2] };
            // sort by k ascending so strict < gives first-occurrence tie-break
            if (k[1] < k[0]) { int tk = k[0]; k[0] = k[1]; k[1] = tk;
                               float td = d[0]; d[0] = d[1]; d[1] = td; }
            if (k[2] < k[1]) { int tk = k[1]; k[1] = k[2]; k[2] = tk;
                               float td = d[1]; d[1] = d[2]; d[2] = td; }
            if (k[1] < k[0]) { int tk = k[0]; k[0] = k[1]; k[1] = tk;
                               float td = d[0]; d[0] = d[1]; d[1] = td; }
            int bk = k[0]; float bd = d[0];
            if (d[1] < bd) { bd = d[1]; bk = k[1]; }
            if (d[2] < bd) { bd = d[2]; bk = k[2]; }
            if (bk != (int)cc.x) {
                int n = base + pt;
                idxf[n] = (float)bk;
                const float* row = cbk + (size_t)bk * DIMS;
                float* oq = out_q + (size_t)bB * DIMS * HW + hw0 + pt;
                for (int dd = 0; dd < DIMS; ++dd)
                    oq[(size_t)dd * HW] = row[dd];
            }
        }
    }
}

// ---- full exact fp32 rescore of rare 3-way-tie points (authoritative) ----
__global__ __launch_bounds__(256) void k_full(const float* __restrict__ latent,
                                              const float* __restrict__ cbkT,
                                              const float* __restrict__ cbk,
                                              const float* __restrict__ c2,
                                              const int* __restrict__ list,
                                              const int* __restrict__ cnt,
                                              float* __restrict__ out_q,
                                              float* __restrict__ idxf) {
    __shared__ float xs[16][200];
    __shared__ float part[16][16];
    __shared__ float inv_s[16];
    __shared__ unsigned long long best[16];
    const int tid = threadIdx.x;
    const int count = *cnt;
    const float4* ct = (const float4*)cbkT;     // [d][256] float4
    const int j = tid >> 4, dl = tid & 15;

    for (int base = blockIdx.x * 16; base < count; base += gridDim.x * 16) {
        __syncthreads();
        float ss = 0.f;
        int n = 0, bb = 0, hw = 0;
        bool valid = (base + j) < count;
        if (valid) {
            n = list[base + j]; bb = n >> 12; hw = n & 4095;
            #pragma unroll
            for (int i = 0; i < 12; ++i) {
                int d = dl + i * 16;
                float v = latent[((size_t)bb * DIMS + d) * HW + hw];
                xs[j][d] = v;
                ss = fmaf(v, v, ss);
            }
        }
        part[j][dl] = ss;
        if (tid < 16) best[tid] = ~0ull;
        __syncthreads();
        if (tid < 16) {
            float s = 0.f;
            #pragma unroll
            for (int i = 0; i < 16; ++i) s += part[tid][i];
            inv_s[tid] = 1.0f / (sqrtf(s) + 1e-8f);
        }
        __syncthreads();

        float4 a[16];
        #pragma unroll
        for (int p = 0; p < 16; ++p) a[p] = make_float4(0.f, 0.f, 0.f, 0.f);
        for (int d = 0; d < DIMS; d += 2) {
            float4 cv0 = ct[(size_t)(d + 0) * 256 + tid];
            float4 cv1 = ct[(size_t)(d + 1) * 256 + tid];
            #pragma unroll
            for (int p = 0; p < 16; ++p) {
                float x0 = xs[p][d], x1 = xs[p][d + 1];
                a[p].x = fmaf(x0, cv0.x, a[p].x); a[p].y = fmaf(x0, cv0.y, a[p].y);
                a[p].z = fmaf(x0, cv0.z, a[p].z); a[p].w = fmaf(x0, cv0.w, a[p].w);
                a[p].x = fmaf(x1, cv1.x, a[p].x); a[p].y = fmaf(x1, cv1.y, a[p].y);
                a[p].z = fmaf(x1, cv1.z, a[p].z); a[p].w = fmaf(x1, cv1.w, a[p].w);
            }
        }
        #pragma unroll
        for (int p = 0; p < 16; ++p) {
            float inv = inv_s[p];
            float dot4[4] = { a[p].x, a[p].y, a[p].z, a[p].w };
            unsigned long long loc = ~0ull;
            #pragma unroll
            for (int e = 0; e < 4; ++e) {
                int k = 4 * tid + e;
                float dist = c2[k] - 2.f * inv * dot4[e];
                unsigned ub = __float_as_uint(dist);
                ub ^= (ub >> 31) ? 0xFFFFFFFFu : 0x80000000u;
                unsigned long long pk = ((unsigned long long)ub << 32) | (unsigned)k;
                loc = loc < pk ? loc : pk;
            }
            #pragma unroll
            for (int off = 1; off < 64; off <<= 1) {
                unsigned long long o = __shfl_xor(loc, off, 64);
                loc = loc < o ? loc : o;
            }
            if ((tid & 63) == 0) atomicMin(&best[p], loc);
        }
        __syncthreads();
        if (valid) {
            int kk = (int)(best[j] & 0xFFFFFFFFull);
            #pragma unroll
            for (int i = 0; i < 12; ++i) {
                int d = dl + i * 16;
                out_q[((size_t)bb * DIMS + d) * HW + hw] = cbk[(size_t)kk * DIMS + d];
            }
            if (dl == 0) idxf[n] = (float)kk;
        }
    }
}

// ======================= fallback fp32 path (round-1) ====================
__global__ __launch_bounds__(256) void k_c2(const float* __restrict__ cbk,
                                            float* __restrict__ c2) {
    int k = blockIdx.x * 256 + threadIdx.x;
    if (k >= KCB) return;
    const float4* row = (const float4*)(cbk + (size_t)k * DIMS);
    float s = 0.f;
    #pragma unroll
    for (int i = 0; i < DIMS / 4; ++i) {
        float4 v = row[i];
        s += v.x * v.x + v.y * v.y + v.z * v.z + v.w * v.w;
    }
    c2[k] = s;
}

__global__ __launch_bounds__(256) void k_norms_fb(const float* __restrict__ latent,
                                                  float* __restrict__ inv_norm) {
    __shared__ float red[256];
    const int tid = threadIdx.x;
    const int n0 = blockIdx.x * 128;
    const int nl = tid & 127;
    const int half = tid >> 7;
    const int b = n0 >> 12;
    const int hw = (n0 & 4095) + nl;
    const float* base = latent + (size_t)b * DIMS * HW + hw;
    float ssq = 0.f;
    for (int c = half; c < DIMS; c += 2) {
        float v = base[(size_t)c * HW];
        ssq = fmaf(v, v, ssq);
    }
    red[tid] = ssq;
    __syncthreads();
    if (half == 0) {
        float s = red[tid] + red[tid + 128];
        inv_norm[n0 + nl] = 1.0f / (sqrtf(s) + 1e-8f);
    }
}

#define LDX  132
__global__ __launch_bounds__(256) void k_dist_fb(const float* __restrict__ latent,
                                                 const float* __restrict__ cbk,
                                                 const float* __restrict__ inv_norm,
                                                 const float* __restrict__ c2,
                                                 int* __restrict__ idx_out,
                                                 float* __restrict__ idxf_out) {
    __shared__ __align__(16) float xsm[64 * LDX];
    __shared__ __align__(16) float csm[64 * LDX];
    __shared__ unsigned long long red[128];
    const int tid = threadIdx.x;
    const int n0 = blockIdx.x * 128;
    const int b = n0 >> 12;
    const int hw0 = n0 & 4095;
    const int kt = tid & 15;
    const int mt = tid >> 4;
    const float* lat_base = latent + (size_t)b * DIMS * HW + hw0;
    float inv[8];
    #pragma unroll
    for (int i = 0; i < 8; ++i) inv[i] = inv_norm[n0 + mt * 8 + i];
    float best[8];
    int bidx[8];
    #pragma unroll
    for (int i = 0; i < 8; ++i) { best[i] = 3.4e38f; bidx[i] = 0; }
    const int nl = tid & 127;
    const int cp = tid >> 7;
    for (int k0 = 0; k0 < KCB; k0 += 128) {
        float acc[8][8];
        #pragma unroll
        for (int i = 0; i < 8; ++i)
            #pragma unroll
            for (int j = 0; j < 8; ++j) acc[i][j] = 0.f;
        for (int d0 = 0; d0 < DIMS; d0 += 64) {
            __syncthreads();
            for (int cc = cp; cc < 64; cc += 2)
                xsm[cc * LDX + nl] = lat_base[(size_t)(d0 + cc) * HW + nl];
            #pragma unroll
            for (int i = 0; i < 8; ++i) {
                int f4 = tid + 256 * i;
                int kk = f4 >> 4;
                int dq = f4 & 15;
                float4 v = *(const float4*)(cbk + (size_t)(k0 + kk) * DIMS + d0 + dq * 4);
                csm[(dq * 4 + 0) * LDX + kk] = v.x;
                csm[(dq * 4 + 1) * LDX + kk] = v.y;
                csm[(dq * 4 + 2) * LDX + kk] = v.z;
                csm[(dq * 4 + 3) * LDX + kk] = v.w;
            }
            __syncthreads();
            for (int d = 0; d < 64; ++d) {
                const float* xr = &xsm[d * LDX + mt * 8];
                const float* cr = &csm[d * LDX + kt * 8];
                float x8[8], c8[8];
                *(float4*)&x8[0] = *(const float4*)&xr[0];
                *(float4*)&x8[4] = *(const float4*)&xr[4];
                *(float4*)&c8[0] = *(const float4*)&cr[0];
                *(float4*)&c8[4] = *(const float4*)&cr[4];
                #pragma unroll
                for (int i = 0; i < 8; ++i)
                    #pragma unroll
                    for (int j = 0; j < 8; ++j)
                        acc[i][j] = fmaf(x8[i], c8[j], acc[i][j]);
            }
        }
        float cc2[8];
        #pragma unroll
        for (int j = 0; j < 8; ++j) cc2[j] = c2[k0 + kt * 8 + j];
        #pragma unroll
        for (int i = 0; i < 8; ++i)
            #pragma unroll
            for (int j = 0; j < 8; ++j) {
                float t = inv[i] * acc[i][j];
                float dist = fmaf(-2.f, t, cc2[j]);
                int kidx = k0 + kt * 8 + j;
                if (dist < best[i]) { best[i] = dist; bidx[i] = kidx; }
            }
    }
    if (tid < 128) red[tid] = ~0ull;
    __syncthreads();
    #pragma unroll
    for (int i = 0; i < 8; ++i) {
        unsigned long long p =
            ((unsigned long long)__float_as_uint(best[i]) << 32) | (unsigned)bidx[i];
        atomicMin(&red[mt * 8 + i], p);
    }
    __syncthreads();
    if (tid < 128) {
        int k = (int)(red[tid] & 0xFFFFFFFFu);
        idx_out[n0 + tid] = k;
        idxf_out[n0 + tid] = (float)k;
    }
}

__global__ __launch_bounds__(256) void k_gather(const float* __restrict__ cbk,
                                                const int* __restrict__ idx,
                                                float* __restrict__ out) {
    __shared__ float q[64 * 193];
    __shared__ int sidx[64];
    const int tid = threadIdx.x;
    const int n0 = blockIdx.x * 64;
    const int b = n0 >> 12;
    const int hw0 = n0 & 4095;
    const int lane = tid & 63;
    const int grp = tid >> 6;

    if (tid < 64) sidx[tid] = idx[n0 + tid];
    __syncthreads();
    for (int r = grp; r < 64; r += 4) {
        const float* row = cbk + (size_t)sidx[r] * DIMS;
        for (int c = lane; c < DIMS; c += 64) q[r * 193 + c] = row[c];
    }
    __syncthreads();
    float* obase = out + (size_t)b * DIMS * HW + hw0;
    for (int c = grp; c < DIMS; c += 4) {
        obase[(size_t)c * HW + lane] = q[lane * 193 + c];
    }
}

// ================================ launch ================================
extern "C" void kernel_launch(void* const* d_in, const int* in_sizes, int n_in,
                              void* d_out, int out_size, void* d_ws, size_t ws_size,
                              hipStream_t stream) {
    const float* latent = (const float*)d_in[0];
    const float* cbk = (const float*)d_in[1];
    float* out = (float*)d_out;
    float* out_q = out;
    float* out_idx = out + QELEMS;

    if (ws_size >= 3u * 1024u * 1024u) {
        // ws layout (bytes):
        char* w = (char*)d_ws;
        _Float16* Bpf = (_Float16*)w;                          //    393,216
        float* cbkT = (float*)(w + 393216);                    //    786,432
        float* c2 = (float*)(w + 1179648);                     //      4,096
        float* inv_g = (float*)(w + 1183744);                  //    262,144
        ushort4* cand4 = (ushort4*)(w + 1445888);              //    524,288
        int* list = (int*)(w + 1970176);                       //    262,144
        int* cnt = (int*)(w + 2232320);                        //          4

        hipMemsetAsync(cnt, 0, 4, stream);
        k_prep<<<KCB / 64, 256, 0, stream>>>(cbk, Bpf, c2, cbkT);
        k_gemm_f2<<<512, 256, 0, stream>>>(latent, Bpf, c2, cbk, out_q, out_idx,
                                           inv_g, cand4, list, cnt);
        k_fix<<<512, 256, 0, stream>>>(latent, cbk, c2, inv_g, cand4,
                                       out_q, out_idx);
        k_full<<<64, 256, 0, stream>>>(latent, cbkT, cbk, c2, list, cnt,
                                       out_q, out_idx);
    } else {
        float* inv_norm = (float*)d_ws;
        float* c2 = inv_norm + NPTS;
        int* idx = (int*)(c2 + KCB);
        k_norms_fb<<<NPTS / 128, 256, 0, stream>>>(latent, inv_norm);
        k_c2<<<4, 256, 0, stream>>>(cbk, c2);
        k_dist_fb<<<NPTS / 128, 256, 0, stream>>>(latent, cbk, inv_norm, c2, idx, out_idx);
        k_gather<<<NPTS / 64, 256, 0, stream>>>(cbk, idx, out_q);
    }
}

// Round 7
// 320.968 us; speedup vs baseline: 1.0627x; 1.0627x over previous
//
#include <hip/hip_runtime.h>
#include <hip/hip_bf16.h>

// Problem: latent (16,192,64,64) fp32, codebook (1024,192) fp32.
// N = 65536 points, D = 192, K = 1024.
// d_out = [quantized: 12582912 fp32][indices-as-float: 65536].

#define NPTS   65536
#define DIMS   192
#define KCB    1024
#define HW     4096
#define QELEMS 12582912

typedef __attribute__((ext_vector_type(8))) _Float16 f16x8;
typedef __attribute__((ext_vector_type(4))) _Float16 f16x4;
typedef __attribute__((ext_vector_type(4))) float f32x4;

// ===================== f16 MFMA path, top-3 + rescue =====================
// A = f16(raw latent) resident in LDS; B = f16(codebook) staged to LDS with
// register-prefetch (next stage loads overlap current stage MFMAs).
// dist+1 = (c2[k]+1) - 2*inv*(A.B) in [~0.998, 4] -> positive float bits
// monotone; k embedded in low 10 mantissa bits (quant <= 4.9e-4).
// f16 dist error E <= 2e-3 (Cauchy-Schwarz). MVAL = 6e-3 >= 2E + q + slack.
//   gap(1,2) < MVAL -> exact fp32 rescore of top-3 candidates (k_fix)
//   gap(1,3) < MVAL -> full 1024-codeword fp32 rescore (k_full), runs last.
#define MVAL 6.0e-3f

__device__ __forceinline__ void ins3(unsigned& a, unsigned& b, unsigned& c,
                                     unsigned v) {
    unsigned m1 = max(a, v); a = min(a, v);
    unsigned m2 = max(b, m1); b = min(b, m1);
    c = min(c, m2);
}

// ---- one-shot prep: Bpf (f16 group-major), c2, cbkT ----
__global__ __launch_bounds__(256) void k_prep(const float* __restrict__ cbk,
                                              _Float16* __restrict__ Bpf,
                                              float* __restrict__ c2,
                                              float* __restrict__ cbkT) {
    __shared__ float q[64 * 193];
    const int tid = threadIdx.x;
    const int k0 = blockIdx.x * 64;
    const int lane = tid & 63;
    const int grp = tid >> 6;
    for (int r = grp; r < 64; r += 4) {
        const float* row = cbk + (size_t)(k0 + r) * DIMS;
        for (int c = lane; c < DIMS; c += 64) q[r * 193 + c] = row[c];
    }
    __syncthreads();
    if (tid < 64) {
        float s = 0.f;
        for (int c = 0; c < DIMS; ++c) { float v = q[tid * 193 + c]; s = fmaf(v, v, s); }
        c2[k0 + tid] = s;
    }
    // Bpf[g][k][64]: g = d>>6
    #pragma unroll
    for (int i = 0; i < 12; ++i) {
        int u = i * 256 + tid;              // 3072 f16x4 units
        int kk = u / 48, c4 = u % 48, d0 = c4 * 4;
        f16x4 h = { (_Float16)q[kk * 193 + d0], (_Float16)q[kk * 193 + d0 + 1],
                    (_Float16)q[kk * 193 + d0 + 2], (_Float16)q[kk * 193 + d0 + 3] };
        *(f16x4*)&Bpf[((size_t)(d0 >> 6) * KCB + k0 + kk) * 64 + (d0 & 63)] = h;
    }
    for (int d = grp; d < DIMS; d += 4)
        cbkT[(size_t)d * KCB + k0 + lane] = q[lane * 193 + d];
}

// ---- fused: latent->f16 LDS + pipelined MFMA + top-3 + gather ----
__global__ __launch_bounds__(256, 2) void k_gemm_f3(const float* __restrict__ latent,
                                                    const _Float16* __restrict__ Bpf,
                                                    const float* __restrict__ c2,
                                                    const float* __restrict__ cbk,
                                                    float* __restrict__ out_q,
                                                    float* __restrict__ idxf,
                                                    float* __restrict__ inv_g,
                                                    ushort4* __restrict__ cand4,
                                                    int* __restrict__ listA,
                                                    int* __restrict__ listB,
                                                    int* __restrict__ cnt2) {
    __shared__ __align__(16) char smem[51200];     // As (K-loop) / t3,q (post)
    _Float16* As = (_Float16*)smem;                // 128 x 200 f16
    __shared__ __align__(16) _Float16 Bs[128 * 64];// 16 KB staged B tile
    __shared__ float part[256];
    __shared__ float inv_s[128];
    __shared__ int sidx[128];

    const int tid = threadIdx.x;
    const int wave = tid >> 6;
    const int lane = tid & 63;
    const int quad = lane >> 4;
    const int l15 = lane & 15;
    const int wm = (wave >> 1) * 64;
    const int wn = (wave & 1) * 64;
    const int n0 = blockIdx.x * 128;
    const int bB = n0 >> 12;
    const int hw0 = n0 & 4095;

    // ---- phase 0: load raw latent slab once, f16-convert, ssq ----
    {
        const float* lat = latent + (size_t)bB * DIMS * HW + hw0;
        const int p = tid & 127, ch = tid >> 7;
        float ss = 0.f;
        #pragma unroll 4
        for (int i = 0; i < 24; ++i) {
            int c0 = i * 8 + ch * 4;
            float v0 = lat[(size_t)(c0 + 0) * HW + p];
            float v1 = lat[(size_t)(c0 + 1) * HW + p];
            float v2 = lat[(size_t)(c0 + 2) * HW + p];
            float v3 = lat[(size_t)(c0 + 3) * HW + p];
            ss = fmaf(v0, v0, fmaf(v1, v1, fmaf(v2, v2, fmaf(v3, v3, ss))));
            f16x4 h = { (_Float16)v0, (_Float16)v1, (_Float16)v2, (_Float16)v3 };
            *(f16x4*)&As[p * 200 + c0] = h;
        }
        part[ch * 128 + p] = ss;
        __syncthreads();
        if (tid < 128) {
            float iv = 1.0f / (sqrtf(part[tid] + part[128 + tid]) + 1e-8f);
            inv_s[tid] = iv;
            inv_g[n0 + tid] = iv;
        }
        __syncthreads();
    }

    // preload -2*inv for this thread's 16 accumulator rows
    float minv[16];
    #pragma unroll
    for (int mt = 0; mt < 4; ++mt)
        #pragma unroll
        for (int r = 0; r < 4; ++r)
            minv[mt * 4 + r] = -2.0f * inv_s[wm + mt * 16 + quad * 4 + r];

    unsigned ra[16], rbv[16], rc[16];
    #pragma unroll
    for (int i = 0; i < 16; ++i) { ra[i] = ~0u; rbv[i] = ~0u; rc[i] = ~0u; }

    // register prefetch of B stage (nb=0, g=0)
    uint4 pre[4];
    #pragma unroll
    for (int i = 0; i < 4; ++i) {
        int u = i * 256 + tid, m = u >> 3, c = u & 7, sw = c ^ (m & 7);
        pre[i] = ((const uint4*)Bpf)[(size_t)((m << 3) + sw)];
    }

    // ---- K-loop: nb (8 strips) x g (3 dim groups), pipelined B staging ----
    for (int nb = 0; nb < 8; ++nb) {
        f32x4 acc[4][4];
        #pragma unroll
        for (int mt = 0; mt < 4; ++mt)
            #pragma unroll
            for (int nt = 0; nt < 4; ++nt)
                #pragma unroll
                for (int r = 0; r < 4; ++r) acc[mt][nt][r] = 0.f;

        #pragma unroll
        for (int g = 0; g < 3; ++g) {
            __syncthreads();                    // prior-stage consumers done
            #pragma unroll
            for (int i = 0; i < 4; ++i)
                ((uint4*)Bs)[i * 256 + tid] = pre[i];
            {   // issue next-stage global loads; overlap with MFMAs below
                int gn = g + 1, nbn = nb;
                if (gn == 3) { gn = 0; nbn = nb + 1; }
                if (nbn < 8) {
                    #pragma unroll
                    for (int i = 0; i < 4; ++i) {
                        int u = i * 256 + tid, m = u >> 3, c = u & 7, sw = c ^ (m & 7);
                        pre[i] = ((const uint4*)Bpf)[
                            (size_t)(((gn * KCB + nbn * 128 + m) << 3) + sw)];
                    }
                }
            }
            __syncthreads();                    // Bs ready (lgkm only)
            #pragma unroll
            for (int s = 0; s < 2; ++s) {
                f16x8 af[4], bfr[4];
                #pragma unroll
                for (int mt = 0; mt < 4; ++mt) {
                    int m = wm + mt * 16 + l15;
                    af[mt] = *(const f16x8*)&As[m * 200 + g * 64 + s * 32 + quad * 8];
                }
                #pragma unroll
                for (int nt = 0; nt < 4; ++nt) {
                    int n = wn + nt * 16 + l15;
                    int cc = (s * 4 + quad) ^ (n & 7);
                    bfr[nt] = *(const f16x8*)&Bs[n * 64 + cc * 8];
                }
                #pragma unroll
                for (int mt = 0; mt < 4; ++mt)
                    #pragma unroll
                    for (int nt = 0; nt < 4; ++nt)
                        acc[mt][nt] = __builtin_amdgcn_mfma_f32_16x16x32_f16(
                            af[mt], bfr[nt], acc[mt][nt], 0, 0, 0);
            }
        }

        // epilogue: u = bits(dist+1) top-22 | k ; insert into sorted top-3
        int kbase = nb * 128 + wn;
        float c2p[4];
        unsigned kc[4];
        #pragma unroll
        for (int nt = 0; nt < 4; ++nt) {
            kc[nt] = (unsigned)(kbase + nt * 16 + l15);
            c2p[nt] = c2[kc[nt]] + 1.0f;
        }
        #pragma unroll
        for (int mt = 0; mt < 4; ++mt) {
            #pragma unroll
            for (int r = 0; r < 4; ++r) {
                int i = mt * 4 + r;
                float mi = minv[i];
                #pragma unroll
                for (int nt = 0; nt < 4; ++nt) {
                    float d1 = fmaf(mi, acc[mt][nt][r], c2p[nt]);
                    unsigned u = (__float_as_uint(d1) & 0xFFFFFC00u) | kc[nt];
                    ins3(ra[i], rbv[i], rc[i], u);
                }
            }
        }
    }

    // ---- cross-lane (16-lane butterfly) top-3 merge ----
    #pragma unroll
    for (int i = 0; i < 16; ++i) {
        unsigned a = ra[i], b = rbv[i], c = rc[i];
        #pragma unroll
        for (int off = 1; off < 16; off <<= 1) {
            unsigned oa = __shfl_xor(a, off, 64);
            unsigned ob = __shfl_xor(b, off, 64);
            unsigned oc = __shfl_xor(c, off, 64);
            ins3(a, b, c, oa); ins3(a, b, c, ob); ins3(a, b, c, oc);
        }
        ra[i] = a; rbv[i] = b; rc[i] = c;
    }
    __syncthreads();                    // As dead; t3 overlays smem
    unsigned* t3 = (unsigned*)smem;     // [128][2][3]
    #pragma unroll
    for (int i = 0; i < 16; ++i) {
        if (l15 == 0) {
            int mt = i >> 2, r = i & 3;
            int m = wm + mt * 16 + quad * 4 + r;
            t3[(m * 2 + (wave & 1)) * 3 + 0] = ra[i];
            t3[(m * 2 + (wave & 1)) * 3 + 1] = rbv[i];
            t3[(m * 2 + (wave & 1)) * 3 + 2] = rc[i];
        }
    }
    __syncthreads();
    if (tid < 128) {
        unsigned a = t3[(tid * 2) * 3], b = t3[(tid * 2) * 3 + 1], c = t3[(tid * 2) * 3 + 2];
        ins3(a, b, c, t3[(tid * 2 + 1) * 3 + 0]);
        ins3(a, b, c, t3[(tid * 2 + 1) * 3 + 1]);
        ins3(a, b, c, t3[(tid * 2 + 1) * 3 + 2]);
        int k1 = (int)(a & 1023u);
        sidx[tid] = k1;
        idxf[n0 + tid] = (float)k1;
        float d1v = __uint_as_float(a & 0xFFFFFC00u);
        float d2v = __uint_as_float(b & 0xFFFFFC00u);
        float d3v = __uint_as_float(c & 0xFFFFFC00u);
        unsigned fl = ((d2v - d1v) < MVAL ? 1u : 0u) | ((d3v - d1v) < MVAL ? 2u : 0u);
        cand4[n0 + tid] = make_ushort4((ushort)k1, (ushort)(b & 1023u),
                                       (ushort)(c & 1023u), (ushort)fl);
        if (fl & 1u) { int pos = atomicAdd(&cnt2[0], 1); listA[pos] = n0 + tid; }
        if (fl & 2u) { int pos = atomicAdd(&cnt2[1], 1); listB[pos] = n0 + tid; }
    }
    __syncthreads();

    // ---- gather epilogue (q overlays smem) ----
    float* q = (float*)smem;            // 32*193*4 = 24.7 KB
    for (int chk = 0; chk < 4; ++chk) {
        int p0 = chk * 32;
        for (int r = wave; r < 32; r += 4) {
            const float* row = cbk + (size_t)sidx[p0 + r] * DIMS;
            for (int c = lane; c < DIMS; c += 64) q[r * 193 + c] = row[c];
        }
        __syncthreads();
        float* ob = out_q + (size_t)bB * DIMS * HW + hw0 + p0;
        #pragma unroll
        for (int i = 0; i < 24; ++i) {
            int u = i * 256 + tid;
            int c = u >> 5, p = u & 31;
            ob[(size_t)c * HW + p] = q[p * 193 + c];
        }
        __syncthreads();
    }
}

// ---- wave-per-point exact fp32 rescore of top-3 candidates ----
__global__ __launch_bounds__(256) void k_fix(const float* __restrict__ latent,
                                             const float* __restrict__ cbk,
                                             const float* __restrict__ c2,
                                             const float* __restrict__ inv_g,
                                             const ushort4* __restrict__ cand4,
                                             const int* __restrict__ listA,
                                             const int* __restrict__ cnt2,
                                             float* __restrict__ out_q,
                                             float* __restrict__ idxf) {
    const int lane = threadIdx.x & 63;
    const int wid = blockIdx.x * 4 + (threadIdx.x >> 6);
    const int count = cnt2[0];
    for (int fi = wid; fi < count; fi += gridDim.x * 4) {
        int n = listA[fi];
        ushort4 cc = cand4[n];
        int bb = n >> 12, hw = n & 4095;
        const float* lp = latent + (size_t)bb * DIMS * HW + hw;
        float x0 = lp[(size_t)(lane) * HW];
        float x1 = lp[(size_t)(lane + 64) * HW];
        float x2 = lp[(size_t)(lane + 128) * HW];
        float inv = inv_g[n];
        int k[3] = { cc.x, cc.y, cc.z };
        // sort by k ascending so strict < gives first-occurrence tie-break
        if (k[1] < k[0]) { int t = k[0]; k[0] = k[1]; k[1] = t; }
        if (k[2] < k[1]) { int t = k[1]; k[1] = k[2]; k[2] = t; }
        if (k[1] < k[0]) { int t = k[0]; k[0] = k[1]; k[1] = t; }
        float d[3];
        #pragma unroll
        for (int j = 0; j < 3; ++j) {
            const float* cr = cbk + (size_t)k[j] * DIMS;
            float t = fmaf(x0, cr[lane],
                      fmaf(x1, cr[lane + 64], x2 * cr[lane + 128]));
            #pragma unroll
            for (int off = 1; off < 64; off <<= 1)
                t += __shfl_xor(t, off, 64);
            d[j] = c2[k[j]] - 2.f * inv * t;
        }
        int bk = k[0]; float bd = d[0];
        if (d[1] < bd) { bd = d[1]; bk = k[1]; }
        if (d[2] < bd) { bd = d[2]; bk = k[2]; }
        if (bk != (int)cc.x) {
            if (lane == 0) idxf[n] = (float)bk;
            const float* cr = cbk + (size_t)bk * DIMS;
            float* oq = out_q + (size_t)bb * DIMS * HW + hw;
            oq[(size_t)(lane) * HW] = cr[lane];
            oq[(size_t)(lane + 64) * HW] = cr[lane + 64];
            oq[(size_t)(lane + 128) * HW] = cr[lane + 128];
        }
    }
}

// ---- full exact fp32 rescore of rare 3-way-tie points (authoritative) ----
__global__ __launch_bounds__(256) void k_full(const float* __restrict__ latent,
                                              const float* __restrict__ cbkT,
                                              const float* __restrict__ cbk,
                                              const float* __restrict__ c2,
                                              const int* __restrict__ listB,
                                              const int* __restrict__ cnt2,
                                              float* __restrict__ out_q,
                                              float* __restrict__ idxf) {
    __shared__ float xs[16][200];
    __shared__ float part[16][16];
    __shared__ float inv_s[16];
    __shared__ unsigned long long best[16];
    const int tid = threadIdx.x;
    const int count = cnt2[1];
    const float4* ct = (const float4*)cbkT;     // [d][256] float4
    const int j = tid >> 4, dl = tid & 15;

    for (int base = blockIdx.x * 16; base < count; base += gridDim.x * 16) {
        __syncthreads();
        float ss = 0.f;
        int n = 0, bb = 0, hw = 0;
        bool valid = (base + j) < count;
        if (valid) {
            n = listB[base + j]; bb = n >> 12; hw = n & 4095;
            #pragma unroll
            for (int i = 0; i < 12; ++i) {
                int d = dl + i * 16;
                float v = latent[((size_t)bb * DIMS + d) * HW + hw];
                xs[j][d] = v;
                ss = fmaf(v, v, ss);
            }
        }
        part[j][dl] = ss;
        if (tid < 16) best[tid] = ~0ull;
        __syncthreads();
        if (tid < 16) {
            float s = 0.f;
            #pragma unroll
            for (int i = 0; i < 16; ++i) s += part[tid][i];
            inv_s[tid] = 1.0f / (sqrtf(s) + 1e-8f);
        }
        __syncthreads();

        float4 a[16];
        #pragma unroll
        for (int p = 0; p < 16; ++p) a[p] = make_float4(0.f, 0.f, 0.f, 0.f);
        for (int d = 0; d < DIMS; d += 2) {
            float4 cv0 = ct[(size_t)(d + 0) * 256 + tid];
            float4 cv1 = ct[(size_t)(d + 1) * 256 + tid];
            #pragma unroll
            for (int p = 0; p < 16; ++p) {
                float x0 = xs[p][d], x1 = xs[p][d + 1];
                a[p].x = fmaf(x0, cv0.x, a[p].x); a[p].y = fmaf(x0, cv0.y, a[p].y);
                a[p].z = fmaf(x0, cv0.z, a[p].z); a[p].w = fmaf(x0, cv0.w, a[p].w);
                a[p].x = fmaf(x1, cv1.x, a[p].x); a[p].y = fmaf(x1, cv1.y, a[p].y);
                a[p].z = fmaf(x1, cv1.z, a[p].z); a[p].w = fmaf(x1, cv1.w, a[p].w);
            }
        }
        #pragma unroll
        for (int p = 0; p < 16; ++p) {
            float inv = inv_s[p];
            float dot4[4] = { a[p].x, a[p].y, a[p].z, a[p].w };
            unsigned long long loc = ~0ull;
            #pragma unroll
            for (int e = 0; e < 4; ++e) {
                int k = 4 * tid + e;
                float dist = c2[k] - 2.f * inv * dot4[e];
                unsigned ub = __float_as_uint(dist);
                ub ^= (ub >> 31) ? 0xFFFFFFFFu : 0x80000000u;
                unsigned long long pk = ((unsigned long long)ub << 32) | (unsigned)k;
                loc = loc < pk ? loc : pk;
            }
            #pragma unroll
            for (int off = 1; off < 64; off <<= 1) {
                unsigned long long o = __shfl_xor(loc, off, 64);
                loc = loc < o ? loc : o;
            }
            if ((tid & 63) == 0) atomicMin(&best[p], loc);
        }
        __syncthreads();
        if (valid) {
            int kk = (int)(best[j] & 0xFFFFFFFFull);
            #pragma unroll
            for (int i = 0; i < 12; ++i) {
                int d = dl + i * 16;
                out_q[((size_t)bb * DIMS + d) * HW + hw] = cbk[(size_t)kk * DIMS + d];
            }
            if (dl == 0) idxf[n] = (float)kk;
        }
    }
}

// ======================= fallback fp32 path (round-1) ====================
__global__ __launch_bounds__(256) void k_c2(const float* __restrict__ cbk,
                                            float* __restrict__ c2) {
    int k = blockIdx.x * 256 + threadIdx.x;
    if (k >= KCB) return;
    const float4* row = (const float4*)(cbk + (size_t)k * DIMS);
    float s = 0.f;
    #pragma unroll
    for (int i = 0; i < DIMS / 4; ++i) {
        float4 v = row[i];
        s += v.x * v.x + v.y * v.y + v.z * v.z + v.w * v.w;
    }
    c2[k] = s;
}

__global__ __launch_bounds__(256) void k_norms_fb(const float* __restrict__ latent,
                                                  float* __restrict__ inv_norm) {
    __shared__ float red[256];
    const int tid = threadIdx.x;
    const int n0 = blockIdx.x * 128;
    const int nl = tid & 127;
    const int half = tid >> 7;
    const int b = n0 >> 12;
    const int hw = (n0 & 4095) + nl;
    const float* base = latent + (size_t)b * DIMS * HW + hw;
    float ssq = 0.f;
    for (int c = half; c < DIMS; c += 2) {
        float v = base[(size_t)c * HW];
        ssq = fmaf(v, v, ssq);
    }
    red[tid] = ssq;
    __syncthreads();
    if (half == 0) {
        float s = red[tid] + red[tid + 128];
        inv_norm[n0 + nl] = 1.0f / (sqrtf(s) + 1e-8f);
    }
}

#define LDX  132
__global__ __launch_bounds__(256) void k_dist_fb(const float* __restrict__ latent,
                                                 const float* __restrict__ cbk,
                                                 const float* __restrict__ inv_norm,
                                                 const float* __restrict__ c2,
                                                 int* __restrict__ idx_out,
                                                 float* __restrict__ idxf_out) {
    __shared__ __align__(16) float xsm[64 * LDX];
    __shared__ __align__(16) float csm[64 * LDX];
    __shared__ unsigned long long red[128];
    const int tid = threadIdx.x;
    const int n0 = blockIdx.x * 128;
    const int b = n0 >> 12;
    const int hw0 = n0 & 4095;
    const int kt = tid & 15;
    const int mt = tid >> 4;
    const float* lat_base = latent + (size_t)b * DIMS * HW + hw0;
    float inv[8];
    #pragma unroll
    for (int i = 0; i < 8; ++i) inv[i] = inv_norm[n0 + mt * 8 + i];
    float best[8];
    int bidx[8];
    #pragma unroll
    for (int i = 0; i < 8; ++i) { best[i] = 3.4e38f; bidx[i] = 0; }
    const int nl = tid & 127;
    const int cp = tid >> 7;
    for (int k0 = 0; k0 < KCB; k0 += 128) {
        float acc[8][8];
        #pragma unroll
        for (int i = 0; i < 8; ++i)
            #pragma unroll
            for (int j = 0; j < 8; ++j) acc[i][j] = 0.f;
        for (int d0 = 0; d0 < DIMS; d0 += 64) {
            __syncthreads();
            for (int cc = cp; cc < 64; cc += 2)
                xsm[cc * LDX + nl] = lat_base[(size_t)(d0 + cc) * HW + nl];
            #pragma unroll
            for (int i = 0; i < 8; ++i) {
                int f4 = tid + 256 * i;
                int kk = f4 >> 4;
                int dq = f4 & 15;
                float4 v = *(const float4*)(cbk + (size_t)(k0 + kk) * DIMS + d0 + dq * 4);
                csm[(dq * 4 + 0) * LDX + kk] = v.x;
                csm[(dq * 4 + 1) * LDX + kk] = v.y;
                csm[(dq * 4 + 2) * LDX + kk] = v.z;
                csm[(dq * 4 + 3) * LDX + kk] = v.w;
            }
            __syncthreads();
            for (int d = 0; d < 64; ++d) {
                const float* xr = &xsm[d * LDX + mt * 8];
                const float* cr = &csm[d * LDX + kt * 8];
                float x8[8], c8[8];
                *(float4*)&x8[0] = *(const float4*)&xr[0];
                *(float4*)&x8[4] = *(const float4*)&xr[4];
                *(float4*)&c8[0] = *(const float4*)&cr[0];
                *(float4*)&c8[4] = *(const float4*)&cr[4];
                #pragma unroll
                for (int i = 0; i < 8; ++i)
                    #pragma unroll
                    for (int j = 0; j < 8; ++j)
                        acc[i][j] = fmaf(x8[i], c8[j], acc[i][j]);
            }
        }
        float cc2[8];
        #pragma unroll
        for (int j = 0; j < 8; ++j) cc2[j] = c2[k0 + kt * 8 + j];
        #pragma unroll
        for (int i = 0; i < 8; ++i)
            #pragma unroll
            for (int j = 0; j < 8; ++j) {
                float t = inv[i] * acc[i][j];
                float dist = fmaf(-2.f, t, cc2[j]);
                int kidx = k0 + kt * 8 + j;
                if (dist < best[i]) { best[i] = dist; bidx[i] = kidx; }
            }
    }
    if (tid < 128) red[tid] = ~0ull;
    __syncthreads();
    #pragma unroll
    for (int i = 0; i < 8; ++i) {
        unsigned long long p =
            ((unsigned long long)__float_as_uint(best[i]) << 32) | (unsigned)bidx[i];
        atomicMin(&red[mt * 8 + i], p);
    }
    __syncthreads();
    if (tid < 128) {
        int k = (int)(red[tid] & 0xFFFFFFFFu);
        idx_out[n0 + tid] = k;
        idxf_out[n0 + tid] = (float)k;
    }
}

__global__ __launch_bounds__(256) void k_gather(const float* __restrict__ cbk,
                                                const int* __restrict__ idx,
                                                float* __restrict__ out) {
    __shared__ float q[64 * 193];
    __shared__ int sidx[64];
    const int tid = threadIdx.x;
    const int n0 = blockIdx.x * 64;
    const int b = n0 >> 12;
    const int hw0 = n0 & 4095;
    const int lane = tid & 63;
    const int grp = tid >> 6;

    if (tid < 64) sidx[tid] = idx[n0 + tid];
    __syncthreads();
    for (int r = grp; r < 64; r += 4) {
        const float* row = cbk + (size_t)sidx[r] * DIMS;
        for (int c = lane; c < DIMS; c += 64) q[r * 193 + c] = row[c];
    }
    __syncthreads();
    float* obase = out + (size_t)b * DIMS * HW + hw0;
    for (int c = grp; c < DIMS; c += 4) {
        obase[(size_t)c * HW + lane] = q[lane * 193 + c];
    }
}

// ================================ launch ================================
extern "C" void kernel_launch(void* const* d_in, const int* in_sizes, int n_in,
                              void* d_out, int out_size, void* d_ws, size_t ws_size,
                              hipStream_t stream) {
    const float* latent = (const float*)d_in[0];
    const float* cbk = (const float*)d_in[1];
    float* out = (float*)d_out;
    float* out_q = out;
    float* out_idx = out + QELEMS;

    if (ws_size >= 3u * 1024u * 1024u) {
        // ws layout (bytes):
        char* w = (char*)d_ws;
        _Float16* Bpf = (_Float16*)w;                          //    393,216
        float* cbkT = (float*)(w + 393216);                    //    786,432
        float* c2 = (float*)(w + 1179648);                     //      4,096
        float* inv_g = (float*)(w + 1183744);                  //    262,144
        ushort4* cand4 = (ushort4*)(w + 1445888);              //    524,288
        int* listA = (int*)(w + 1970176);                      //    262,144
        int* listB = (int*)(w + 2232320);                      //    262,144
        int* cnt2 = (int*)(w + 2494464);                       //          8

        hipMemsetAsync(cnt2, 0, 8, stream);
        k_prep<<<KCB / 64, 256, 0, stream>>>(cbk, Bpf, c2, cbkT);
        k_gemm_f3<<<512, 256, 0, stream>>>(latent, Bpf, c2, cbk, out_q, out_idx,
                                           inv_g, cand4, listA, listB, cnt2);
        k_fix<<<1024, 256, 0, stream>>>(latent, cbk, c2, inv_g, cand4, listA,
                                        cnt2, out_q, out_idx);
        k_full<<<64, 256, 0, stream>>>(latent, cbkT, cbk, c2, listB, cnt2,
                                       out_q, out_idx);
    } else {
        float* inv_norm = (float*)d_ws;
        float* c2 = inv_norm + NPTS;
        int* idx = (int*)(c2 + KCB);
        k_norms_fb<<<NPTS / 128, 256, 0, stream>>>(latent, inv_norm);
        k_c2<<<4, 256, 0, stream>>>(cbk, c2);
        k_dist_fb<<<NPTS / 128, 256, 0, stream>>>(latent, cbk, inv_norm, c2, idx, out_idx);
        k_gather<<<NPTS / 64, 256, 0, stream>>>(cbk, idx, out_q);
    }
}